// Round 10
// baseline (146.696 us; speedup 1.0000x reference)
//
#include <hip/hip_runtime.h>
#include <math.h>

// Problem constants (reference: B=4, S=2048, E=384, H=8, D=48)
#define B_ 4
#define S_ 2048
#define E_ 384
#define H_ 8
#define D_ 48
#define M_ (B_*S_)            // 8192 rows
#define DP_ 64                // padded head dim in Qp/Kp
constexpr float QK_SCALE = 0.14433756729740643f * 1.4426950408889634f; // 1/sqrt(48) * log2(e)

typedef __attribute__((ext_vector_type(8))) short short8;   // 8 bf16 = 4 VGPRs
typedef __attribute__((ext_vector_type(4))) float f32x4;
typedef __attribute__((ext_vector_type(4))) unsigned uint4v;
typedef unsigned short u16;

__device__ inline u16 f2bf(float f) {            // RNE fp32->bf16
    unsigned u = __float_as_uint(f);
    return (u16)((u + 0x7FFFu + ((u >> 16) & 1u)) >> 16);
}
__device__ inline float bf2f(u16 h) { return __uint_as_float(((unsigned)h) << 16); }
__device__ inline unsigned pk2(float a, float b) {
    return (unsigned)f2bf(a) | ((unsigned)f2bf(b) << 16);
}
// round-half-up packed fp32x2 -> bf16x2 (1 perm + 2 adds)
__device__ inline unsigned pk2_fast(float a, float b) {
#if __has_builtin(__builtin_amdgcn_perm)
    unsigned ua = __float_as_uint(a) + 0x8000u;
    unsigned ub = __float_as_uint(b) + 0x8000u;
    return __builtin_amdgcn_perm(ub, ua, 0x07060302u);
#else
    return pk2(a, b);
#endif
}
__device__ inline float fexp2(float x) {
#if __has_builtin(__builtin_amdgcn_exp2f)
    return __builtin_amdgcn_exp2f(x);
#else
    return exp2f(x);
#endif
}
__device__ inline void glld16(const void* g, void* l) {
    __builtin_amdgcn_global_load_lds((const __attribute__((address_space(1))) unsigned int*)g,
                                     (__attribute__((address_space(3))) unsigned int*)l, 16, 0, 0);
}
// lane-row swaps (gfx950): a[32:63] <-> b[0:31]
__device__ inline void plswap32(unsigned &a, unsigned &b) {
#if __has_builtin(__builtin_amdgcn_permlane32_swap)
    auto r = __builtin_amdgcn_permlane32_swap(a, b, false, false);
    a = r[0]; b = r[1];
#else
    asm volatile("v_permlane32_swap_b32 %0, %1" : "+v"(a), "+v"(b));
#endif
}
// a odd-16-groups <-> b even-16-groups
__device__ inline void plswap16(unsigned &a, unsigned &b) {
#if __has_builtin(__builtin_amdgcn_permlane16_swap)
    auto r = __builtin_amdgcn_permlane16_swap(a, b, false, false);
    a = r[0]; b = r[1];
#else
    asm volatile("v_permlane16_swap_b32 %0, %1" : "+v"(a), "+v"(b));
#endif
}

// ---------------------------------------------------------------------------
// Fused prep: x->bf16 | weights->bf16 | Q/K pad columns.
// grid = 3072 (x) + 144 (w) + 256 (pad) = 3472 blocks.
// ---------------------------------------------------------------------------
__global__ __launch_bounds__(256) void prep(const float4* __restrict__ x,
                                            const int* __restrict__ mask,
                                            const float4* __restrict__ wq,
                                            const float4* __restrict__ wk,
                                            const float4* __restrict__ wv,
                                            const float4* __restrict__ wo,
                                            uint2* __restrict__ xb,
                                            uint2* __restrict__ wb,
                                            u16* __restrict__ Qp, u16* __restrict__ Kp) {
    const int bx = blockIdx.x, t = threadIdx.x;
    if (bx < 3072) {                               // x: NELEM/4 = 786432
        int i = bx * 256 + t;
        float4 v = x[i];
        uint2 H;
        H.x = pk2(v.x, v.y);
        H.y = pk2(v.z, v.w);
        xb[i] = H;
    } else if (bx < 3072 + 144) {                  // weights: WELEM/4 = 36864 each
        int i = (bx - 3072) * 256 + t;
        const int n4 = 36864;
        const float4* srcs[4] = {wq, wk, wv, wo};
        #pragma unroll
        for (int j = 0; j < 4; ++j) {
            float4 v = srcs[j][i];
            uint2 H;
            H.x = pk2(v.x, v.y);
            H.y = pk2(v.z, v.w);
            wb[(size_t)j * n4 + i] = H;
        }
    } else {                                       // pad cols 48..63 of Qp/Kp
        int i = (bx - 3216) * 256 + t;             // over BH*S = 65536
        int bh = i >> 11, s = i & 2047, b = bh >> 3;
        size_t off = ((size_t)bh * S_ + s) * DP_ + 48;
        uint4 qz = {0x00004300u, 0, 0, 0};         // col48 = 128.0, rest 0
        uint4 kz = {mask[b * S_ + s] ? 0x0000BF80u : 0u, 0, 0, 0}; // col48 = -1/0
        uint4 z  = {0, 0, 0, 0};
        *reinterpret_cast<uint4*>(Qp + off)     = qz;
        *reinterpret_cast<uint4*>(Qp + off + 8) = z;
        *reinterpret_cast<uint4*>(Kp + off)     = kz;
        *reinterpret_cast<uint4*>(Kp + off + 8) = z;
    }
}

// ---------------------------------------------------------------------------
// FUSED QKV GEMM: one 64m x 64n tile for ALL THREE weights (x staged once).
// grid (M/64, 6). LDS 32 KB single-buffered -> 3 blocks/CU (grid-limited).
// R9 revision: T14 async-stage pipeline. Old per-iter structure was
// stage -> barrier+vmcnt(0) DRAIN -> compute: full global latency on the
// critical path 6x/block. Now: global loads for k+1 issue into REGISTERS
// before compute(k); ds_write after the read-barrier. Latency hides under
// ~400cyc of MFMA. LDS stays 32 KB (explicit dbuf would drop 3->2 blocks/CU).
// Epilogues: V -> [bh][d][s] direct; Q/K -> LDS transpose -> [bh][s][64].
// ---------------------------------------------------------------------------
__global__ __launch_bounds__(256) void gemm_qkv3(const u16* __restrict__ xb,
                                                 const u16* __restrict__ wb,
                                                 const float* __restrict__ bq,
                                                 const float* __restrict__ bk,
                                                 const float* __restrict__ bv,
                                                 u16* __restrict__ Qp, u16* __restrict__ Kp,
                                                 u16* __restrict__ Vtp) {
    __shared__ u16 smem[4 * 4096];                 // As | WsQ | WsK | WsV (32 KB)
    u16* As = smem;

    const int t = threadIdx.x, w = t >> 6, lane = t & 63;
    const int ln = lane & 15, quad = lane >> 4;
    const int gr = lane >> 3;
    const int gc = (lane & 7) ^ gr;
    const int m0 = blockIdx.x * 64;
    const int n0 = blockIdx.y * 64;
    const int b  = m0 >> 11;                       // 64-row block never straddles batch

    // per-lane global sources (element offsets; advance by kk per iter)
    const u16* aSrc = xb + (size_t)(m0 + w * 16 + gr) * E_ + gc * 8;
    const u16* wSrc0 = wb + (size_t)0 * 147456 + (size_t)(n0 + w * 16 + gr) * E_ + gc * 8;
    const u16* wSrc1 = wb + (size_t)1 * 147456 + (size_t)(n0 + w * 16 + gr) * E_ + gc * 8;
    const u16* wSrc2 = wb + (size_t)2 * 147456 + (size_t)(n0 + w * 16 + gr) * E_ + gc * 8;

    f32x4 acc[3][4];
    #pragma unroll
    for (int j = 0; j < 3; ++j)
        #pragma unroll
        for (int nt = 0; nt < 4; ++nt)
            acc[j][nt] = (f32x4){0.f, 0.f, 0.f, 0.f};

    short8 rA0, rA1, rW[3][2];
    auto loads = [&](int kk) {                     // issue only; no waits here
        rA0 = *reinterpret_cast<const short8*>(aSrc + kk);
        rA1 = *reinterpret_cast<const short8*>(aSrc + 8 * E_ + kk);
        #pragma unroll
        for (int i = 0; i < 2; ++i) {
            rW[0][i] = *reinterpret_cast<const short8*>(wSrc0 + i * 8 * E_ + kk);
            rW[1][i] = *reinterpret_cast<const short8*>(wSrc1 + i * 8 * E_ + kk);
            rW[2][i] = *reinterpret_cast<const short8*>(wSrc2 + i * 8 * E_ + kk);
        }
    };
    auto writes = [&]() {                          // regs -> LDS (same layout as glld16)
        *reinterpret_cast<short8*>(As + (w * 16) * 64 + lane * 8)     = rA0;
        *reinterpret_cast<short8*>(As + (w * 16 + 8) * 64 + lane * 8) = rA1;
        #pragma unroll
        for (int j = 0; j < 3; ++j)
            #pragma unroll
            for (int i = 0; i < 2; ++i)
                *reinterpret_cast<short8*>(smem + (1 + j) * 4096 +
                                           (w * 16 + i * 8) * 64 + lane * 8) = rW[j][i];
    };

    loads(0);
    writes();
    __syncthreads();

    #pragma unroll
    for (int it = 0; it < 6; ++it) {
        if (it < 5) loads((it + 1) * 64);          // latency hides under compute

        #pragma unroll
        for (int ks = 0; ks < 2; ++ks) {
            const int slot = (ks * 4 + quad) ^ (ln & 7);
            short8 ah = *reinterpret_cast<const short8*>(&As[(w * 16 + ln) * 64 + slot * 8]);
            #pragma unroll
            for (int j = 0; j < 3; ++j) {
                const u16* Wsj = smem + (1 + j) * 4096;
                #pragma unroll
                for (int nt = 0; nt < 4; ++nt) {
                    short8 wf = *reinterpret_cast<const short8*>(&Wsj[(nt * 16 + ln) * 64 + slot * 8]);
                    acc[j][nt] = __builtin_amdgcn_mfma_f32_16x16x32_bf16(ah, wf, acc[j][nt], 0, 0, 0);
                }
            }
        }
        __syncthreads();                           // all reads of this k done
        if (it < 5) {
            writes();                              // vmcnt waits land here (post-compute)
            __syncthreads();                       // buffer ready for next iter
        }
    }

    // ---- V epilogue: [bh][d][s], 4 s-consecutive packed per 8B store ----
    {
        const int s_base = (m0 & 2047) + w * 16 + quad * 4;
        #pragma unroll
        for (int nt = 0; nt < 4; ++nt) {
            const int col = n0 + nt * 16 + ln;
            const int h   = (col * 683) >> 15;     // col / 48
            const int d   = col - h * 48;
            const float bc = bv[col];
            u16* dst = Vtp + ((size_t)(b * 8 + h) * 48 + d) * 2048;
            uint2 pk;
            pk.x = pk2(acc[2][nt][0] + bc, acc[2][nt][1] + bc);
            pk.y = pk2(acc[2][nt][2] + bc, acc[2][nt][3] + bc);
            *reinterpret_cast<uint2*>(dst + s_base) = pk;
        }
    }

    // ---- Q/K epilogue: transpose both through LDS, coalesced 16B stores ----
    u16* TrQ = smem;                               // [64][76] = 9728 B
    u16* TrK = smem + 64 * 76;                     // [64][76] (total 19456 B < 32 KB)
    __syncthreads();                               // frag reads done before overwrite
    #pragma unroll
    for (int nt = 0; nt < 4; ++nt) {
        const int col = n0 + nt * 16 + ln;
        const float bcq = bq[col], bck = bk[col];
        #pragma unroll
        for (int r = 0; r < 4; ++r) {
            int row = w * 16 + quad * 4 + r;
            TrQ[row * 76 + nt * 16 + ln] = f2bf((acc[0][nt][r] + bcq) * QK_SCALE);
            TrK[row * 76 + nt * 16 + ln] = f2bf(acc[1][nt][r] + bck);
        }
    }
    __syncthreads();
    {
        const int row = t >> 2, quarter = t & 3;
        const int s   = (m0 & 2047) + row;
        #pragma unroll
        for (int c = 0; c < 2; ++c) {
            int gcol = n0 + quarter * 16 + c * 8;  // 8-col chunk never straddles a head
            int h = (gcol * 683) >> 15;
            int d = gcol - h * 48;
            size_t off = ((size_t)(b * 8 + h) * 2048 + s) * DP_ + d;
            *reinterpret_cast<uint4*>(Qp + off) =
                *reinterpret_cast<const uint4*>(&TrQ[row * 76 + quarter * 16 + c * 8]);
            *reinterpret_cast<uint4*>(Kp + off) =
                *reinterpret_cast<const uint4*>(&TrK[row * 76 + quarter * 16 + c * 8]);
        }
    }
}

// ---------------------------------------------------------------------------
// O-proj: 64-row tiles, double-buffered, fp32 out.
// ---------------------------------------------------------------------------
__global__ __launch_bounds__(256) void gemm_out(const u16* __restrict__ ab,
                                                const u16* __restrict__ wb,
                                                const float* __restrict__ bo, float* __restrict__ out) {
    __shared__ u16 smem[2 * 4096 + 2 * 4096];          // 32 KB
    u16* As = smem;
    u16* Ws = smem + 2 * 4096;
    const int t = threadIdx.x, w = t >> 6, lane = t & 63;
    const int ln = lane & 15, quad = lane >> 4;
    const int gr = lane >> 3;
    const int gc = (lane & 7) ^ gr;
    const int m0 = blockIdx.x * 64, n0 = blockIdx.y * 64;
    const u16* wh = wb + (size_t)3 * 147456;

    f32x4 acc[4];
    #pragma unroll
    for (int nt = 0; nt < 4; ++nt) acc[nt] = (f32x4){0.f, 0.f, 0.f, 0.f};

    auto stage = [&](int bf, int kk) {
        #pragma unroll
        for (int i = 0; i < 2; ++i) {
            int r0 = w * 16 + i * 8;
            glld16(ab + (size_t)(m0 + r0 + gr) * E_ + kk + gc * 8, As + bf * 4096 + r0 * 64);
            glld16(wh + (size_t)(n0 + r0 + gr) * E_ + kk + gc * 8, Ws + bf * 4096 + r0 * 64);
        }
    };

    stage(0, 0);
    __syncthreads();
    #pragma unroll
    for (int it = 0; it < 6; ++it) {
        const int cur = it & 1;
        if (it < 5) stage(cur ^ 1, (it + 1) * 64);
        const u16* Ab = As + cur * 4096;
        const u16* Wb = Ws + cur * 4096;
        #pragma unroll
        for (int ks = 0; ks < 2; ++ks) {
            const int slot = (ks * 4 + quad) ^ (ln & 7);
            short8 ah = *reinterpret_cast<const short8*>(&Ab[(w * 16 + ln) * 64 + slot * 8]);
            #pragma unroll
            for (int nt = 0; nt < 4; ++nt) {
                short8 wf = *reinterpret_cast<const short8*>(&Wb[(nt * 16 + ln) * 64 + slot * 8]);
                acc[nt] = __builtin_amdgcn_mfma_f32_16x16x32_bf16(ah, wf, acc[nt], 0, 0, 0);
            }
        }
        __syncthreads();
    }

    #pragma unroll
    for (int nt = 0; nt < 4; ++nt) {
        const int col = n0 + nt * 16 + ln;
        const float bc = bo[col];
        #pragma unroll
        for (int r = 0; r < 4; ++r) {
            size_t row = (size_t)(m0 + w * 16 + quad * 4 + r);
            out[row * E_ + col] = acc[nt][r] + bc;
        }
    }
}

// ---------------------------------------------------------------------------
// MFMA flash attention. Static softmax; mask folded into pad column.
// Grid (bh, q-tile): id%8 = bh%8 -> all q-tiles of one head share an XCD.
// 8 waves x 16 q-rows (512 threads), 2 blocks/CU. KVBLK=128 (R9: 49->46us).
// R9 rider fix: the 128-col V^T buffer measured 3.1M bank-conflict cycles
// (384/block-body, ~4cyc per V ds_read) where R7's 64-col layout measured 0.
// Static bank model failed to predict this -> empirical fix: V^T as TWO
// 64-col half-buffers (R7's proven-conflict-free pattern), same keys/volume.
// ---------------------------------------------------------------------------
__global__ __launch_bounds__(512, 4) void attn_mfma(const u16* __restrict__ Qp,
                                                    const u16* __restrict__ Kp,
                                                    const u16* __restrict__ Vtp,
                                                    u16* __restrict__ AO) {
    __shared__ __align__(16) u16 QPs[128 * 64];     // Q (16 KB)
    __shared__ __align__(16) u16 Ksh[2][128 * 64];  // K double buffer (32 KB)
    __shared__ __align__(16) u16 Vt[2][2][48 * 64]; // V^T dbuf, 2 key-halves (24 KB)
    __shared__ float linv[8][16];

    const int t    = threadIdx.x;
    const int w    = t >> 6;                        // 0..7
    const int lane = t & 63;
    const int ln   = lane & 15;
    const int quad = lane >> 4;
    const int gr   = lane >> 3;                     // staging row within 8
    const int gc   = (lane & 7) ^ gr;               // staging swizzled chunk
    const int bh   = blockIdx.x;                    // XCD-locality: id%8 = bh%8
    const int q0   = blockIdx.y * 128;
    const int b    = bh >> 3, h = bh & 7;
    const int cb   = h * 48;
    const size_t rb = (size_t)b * S_;

    const u16* Qsrc = Qp  + ((size_t)bh * S_ + q0) * DP_;
    const u16* Ksrc = Kp  + (size_t)bh * S_ * DP_;
    const u16* Vsrc = Vtp + (size_t)bh * 48 * 2048;

    // ---- hoisted LDS read addresses ----
    const int swz0 = ((quad    ) ^ (ln & 7)) << 3;
    const int swz1 = ((4 + quad) ^ (ln & 7)) << 3;
    const u16* kA[2][2];
    const u16* vA[2][4];                            // [buf][key-group g]
    #pragma unroll
    for (int bf = 0; bf < 2; ++bf) {
        kA[bf][0] = &Ksh[bf][ln * 64 + swz0];
        kA[bf][1] = &Ksh[bf][ln * 64 + swz1];
        #pragma unroll
        for (int g = 0; g < 4; ++g)
            vA[bf][g] = &Vt[bf][g >> 1][ln * 64 + ((((g & 1) * 4 + quad) ^ (ln & 7)) << 3)];
    }
    const int qrow = (w * 16 + ln) * 64;            // this wave's 16 q-rows
    const u16* pR[2];
    pR[0] = &QPs[qrow + swz0];
    pR[1] = &QPs[qrow + swz1];

    // ---- staging one 128-key tile: K rows w*16..+16 (all 8 waves);
    //      V halves 0,1 rows w*8..+8 (waves 0-5, R7 pattern per half) ----
    auto stage = [&](int bf, int kt) {
        const int k0 = kt * 128;
        #pragma unroll
        for (int i = 0; i < 2; ++i)
            glld16(Ksrc + (size_t)(k0 + w * 16 + i * 8 + gr) * DP_ + gc * 8,
                   &Ksh[bf][(w * 16 + i * 8) * 64]);
        if (w < 6) {
            glld16(Vsrc + (size_t)(w * 8 + gr) * 2048 + k0 + gc * 8,      &Vt[bf][0][(w * 8) * 64]);
            glld16(Vsrc + (size_t)(w * 8 + gr) * 2048 + k0 + 64 + gc * 8, &Vt[bf][1][(w * 8) * 64]);
        }
    };

    // ---- prologue: stage Q (own 16 rows) + tile 0 ----
    #pragma unroll
    for (int i = 0; i < 2; ++i) {
        int r0 = w * 16 + i * 8;
        glld16(Qsrc + (size_t)(r0 + gr) * DP_ + gc * 8, &QPs[r0 * 64]);
    }
    stage(0, 0);
    __syncthreads();

    short8 qf[2];
    qf[0] = *reinterpret_cast<const short8*>(pR[0]);
    qf[1] = *reinterpret_cast<const short8*>(pR[1]);

    f32x4 o[3];
    #pragma unroll
    for (int nt = 0; nt < 3; ++nt) o[nt] = (f32x4){0.f, 0.f, 0.f, 0.f};
    float lq = 0.f;

    auto body = [&](int cur, int nxt, int ktn) {
        if (ktn < 16) stage(nxt, ktn);              // prefetch; drained by end barrier

        short8 pa[4];                               // P frags for 4x32-key groups
        // ---- two 64-key halves: QK -> exp/pack -> in-register transpose ----
        #pragma unroll
        for (int hf = 0; hf < 2; ++hf) {
            f32x4 sc[4];
            #pragma unroll
            for (int m = 0; m < 4; ++m) {
                const int Mt = hf * 4 + m;
                short8 kf0 = *reinterpret_cast<const short8*>(kA[cur][0] + Mt * 1024);
                short8 kf1 = *reinterpret_cast<const short8*>(kA[cur][1] + Mt * 1024);
                f32x4 a0 = __builtin_amdgcn_mfma_f32_16x16x32_bf16(kf0, qf[0], (f32x4){0.f,0.f,0.f,0.f}, 0, 0, 0);
                sc[m] = __builtin_amdgcn_mfma_f32_16x16x32_bf16(kf1, qf[1], a0, 0, 0, 0);
            }
            unsigned U[4][2];
            #pragma unroll
            for (int m = 0; m < 4; ++m) {
                float p0 = fexp2(sc[m][0]);
                float p1 = fexp2(sc[m][1]);
                float p2 = fexp2(sc[m][2]);
                float p3 = fexp2(sc[m][3]);
                lq += (p0 + p1) + (p2 + p3);
                U[m][0] = pk2_fast(p0, p1);
                U[m][1] = pk2_fast(p2, p3);
            }
            #pragma unroll
            for (int g = 0; g < 2; ++g) {
                unsigned a0 = U[g * 2][0], b0 = U[g * 2 + 1][0];
                plswap32(a0, b0); plswap16(a0, b0);
                unsigned a1 = U[g * 2][1], b1 = U[g * 2 + 1][1];
                plswap32(a1, b1); plswap16(a1, b1);
                uint4v uv = {a0, a1, b0, b1};
                pa[hf * 2 + g] = __builtin_bit_cast(short8, uv);
            }
        }

        // ---- PV: 4 key-groups x 3 d-tiles ----
        #pragma unroll
        for (int nt = 0; nt < 3; ++nt)
            #pragma unroll
            for (int g = 0; g < 4; ++g) {
                short8 vb = *reinterpret_cast<const short8*>(vA[cur][g] + nt * 1024);
                o[nt] = __builtin_amdgcn_mfma_f32_16x16x32_bf16(pa[g], vb, o[nt], 0, 0, 0);
            }
        __syncthreads();                            // staging of nxt complete
    };

    for (int kt = 0; kt < 16; kt += 2) {            // 16 tiles of 128 keys
        body(0, 1, kt + 1);
        body(1, 0, kt + 2);
    }

    // ---- epilogue: reduce l across quads, divide, store bf16 AO ----
    {
        float l = lq;
        l += __shfl_xor(l, 16);
        l += __shfl_xor(l, 32);
        if (quad == 0) linv[w][ln] = 1.0f / l;
    }
    __syncthreads();
    {
        f32x4 il = *reinterpret_cast<const f32x4*>(&linv[w][quad * 4]);
        #pragma unroll
        for (int nt = 0; nt < 3; ++nt)
            #pragma unroll
            for (int r = 0; r < 4; ++r) {
                size_t row = rb + q0 + w * 16 + quad * 4 + r;
                size_t idx = row * E_ + cb + nt * 16 + ln;
                AO[idx] = f2bf(o[nt][r] * il[r]);
            }
    }
}

// ---------------------------------------------------------------------------
extern "C" void kernel_launch(void* const* d_in, const int* in_sizes, int n_in,
                              void* d_out, int out_size, void* d_ws, size_t ws_size,
                              hipStream_t stream) {
    (void)in_sizes; (void)n_in; (void)out_size; (void)ws_size;
    const float* x    = (const float*)d_in[0];
    const int*   mask = (const int*)  d_in[1];
    const float* Wq   = (const float*)d_in[2];
    const float* bq   = (const float*)d_in[3];
    const float* Wk   = (const float*)d_in[4];
    const float* bk   = (const float*)d_in[5];
    const float* Wv   = (const float*)d_in[6];
    const float* bv   = (const float*)d_in[7];
    const float* Wo   = (const float*)d_in[8];
    const float* bo   = (const float*)d_in[9];

    const size_t NELEM = (size_t)M_ * E_;        // 3,145,728
    const size_t WELEM = (size_t)E_ * E_;        // 147,456
    const size_t PEL   = (size_t)B_ * H_ * S_ * DP_;  // 4,194,304
    u16* ws = (u16*)d_ws;
    u16* xb  = ws;                                // NELEM (reused as AO)
    u16* wb  = xb + NELEM;                        // 4*WELEM
    u16* Qp  = wb + 4 * WELEM;                    // PEL
    u16* Kp  = Qp + PEL;                          // PEL
    u16* Vtp = Kp + PEL;                          // NELEM ([bh][48][2048])
    u16* AO  = xb;                                // alias: xb dead after gemm_qkv3

    dim3 blk(256);
    prep<<<dim3(3472), blk, 0, stream>>>(
        (const float4*)x, mask,
        (const float4*)Wq, (const float4*)Wk, (const float4*)Wv, (const float4*)Wo,
        (uint2*)xb, (uint2*)wb, Qp, Kp);

    gemm_qkv3<<<dim3(M_ / 64, 6), blk, 0, stream>>>(xb, wb, bq, bk, bv, Qp, Kp, Vtp);

    attn_mfma<<<dim3(B_ * H_, S_ / 128), dim3(512), 0, stream>>>(Qp, Kp, Vtp, AO);

    gemm_out<<<dim3(M_ / 64, 6), blk, 0, stream>>>(AO, wb, bo, (float*)d_out);
}